// Round 5
// baseline (664.931 us; speedup 1.0000x reference)
//
#include <hip/hip_runtime.h>
#include <hip/hip_bf16.h>

#define NE 8
#define NT 16384
#define ND 512
#define NF 2048
#define BT 128

typedef __attribute__((ext_vector_type(8))) short bf16x8;
typedef __attribute__((ext_vector_type(4))) float f32x4;
typedef unsigned short u16;
typedef unsigned long long u64;

#define WAITV(n) asm volatile("s_waitcnt vmcnt(" #n ")" ::: "memory")

__device__ __forceinline__ u16 f2bf(float f) {
  union { float f; unsigned u; } c; c.f = f;
  unsigned u = c.u;
  return (u16)((u + 0x7FFFu + ((u >> 16) & 1u)) >> 16);
}

// gelu(x) = x * (1 - 1/(exp2(K1*x + K2*x^3) + 1)),  K1 = sqrt(2/pi)*2*log2e
__device__ __forceinline__ float gelu_fast(float x) {
  float x2 = x * x;
  float zp = x * __builtin_fmaf(0.10294325f, x2, 2.3022084f);
  float u = __builtin_amdgcn_exp2f(zp);
  float r = __builtin_amdgcn_rcpf(u + 1.0f);   // u=inf -> r=0 -> y=x
  return x * (1.0f - r);
}

__device__ __forceinline__ void gl_lds16(const void* g, void* l) {
  __builtin_amdgcn_global_load_lds(
      (const __attribute__((address_space(1))) unsigned int*)g,
      (__attribute__((address_space(3))) unsigned int*)l, 16, 0, 0);
}

// Pack weights into staged-panel images (swizzle pre-applied, byte-exact LDS image).
// MODE 0: W1 [E][512 d][2048 f] -> panels (e, c=f/256, kb=d/32): [256 f][32 d] bf16, 16 KB.
// MODE 1: W2 [E][2048 f][512 d] -> panels (e, c=f/256, kb=(f%256)/32): [512 d][32 f] bf16, 32 KB.
template<int MODE>
__global__ void pack_w(const float* __restrict__ in, u16* __restrict__ outp) {
  constexpr int K = MODE ? 2048 : 512;
  constexpr int R = MODE ? 512 : 2048;
  __shared__ float tile[32][33];
  int e = blockIdx.z, bx = blockIdx.x, by = blockIdx.y;
  int k0 = bx * 32, r0 = by * 32;
  int tx = threadIdx.x & 31, ty = threadIdx.x >> 5;
  const float* ip = in + ((size_t)e * K + k0) * R + r0;
  #pragma unroll
  for (int i = 0; i < 4; i++)
    tile[ty + i * 8][tx] = ip[(size_t)(ty + i * 8) * R + tx];
  __syncthreads();
  size_t base; int rowb;
  if (MODE == 0) { base = (((size_t)e * 8 + (by >> 3)) * 16 + bx) * 8192; rowb = (by & 7) * 32; }
  else           { base = (((size_t)e * 8 + (bx >> 3)) * 8 + (bx & 7)) * 16384; rowb = by * 32; }
  int row = rowb + tx;
  int byo = row * 64 + ((ty * 8) ^ (((row >> 1) & 3) << 4));
  union { u16 s[4]; ushort4 v; } o;
  #pragma unroll
  for (int j = 0; j < 4; j++) o.s[j] = f2bf(tile[ty * 4 + j][tx]);
  *(ushort4*)((char*)outp + base * 2 + byo) = o.v;
}

__global__ void x_to_bf16(const float* __restrict__ x, u16* __restrict__ xbf) {
  int i = blockIdx.x * 256 + threadIdx.x;
  float4 v = ((const float4*)x)[i];
  union { u16 s[4]; u64 ll; } o;
  o.s[0] = f2bf(v.x); o.s[1] = f2bf(v.y); o.s[2] = f2bf(v.z); o.s[3] = f2bf(v.w);
  ((u64*)xbf)[i] = o.ll;
}

__global__ void zero_unmasked(const int* __restrict__ mask, float4* __restrict__ out4) {
  int row = blockIdx.x * 2 + (threadIdx.x >> 7);
  if (mask[row]) return;  // masked rows fully written by moe_ffn
  out4[(size_t)row * 128 + (threadIdx.x & 127)] = float4{0.f, 0.f, 0.f, 0.f};
}

__global__ void compact_mask(const int* __restrict__ mask, int* __restrict__ idx,
                             int* __restrict__ counts) {
  int e = blockIdx.x;
  __shared__ int wsum[4];
  __shared__ int base;
  if (threadIdx.x == 0) base = 0;
  const int* m = mask + (size_t)e * NT;
  int lane = threadIdx.x & 63, w = threadIdx.x >> 6;
  for (int c0 = 0; c0 < NT; c0 += 256) {
    __syncthreads();
    int i = c0 + threadIdx.x;
    int mi = (m[i] != 0);
    unsigned long long b = __ballot(mi);
    if (lane == 0) wsum[w] = __popcll(b);
    __syncthreads();
    int off = base;
    for (int ww = 0; ww < w; ww++) off += wsum[ww];
    off += __popcll(b & ((1ull << lane) - 1ull));
    if (mi) idx[(size_t)e * NT + off] = i;
    __syncthreads();
    if (threadIdx.x == 0) base += wsum[0] + wsum[1] + wsum[2] + wsum[3];
  }
  __syncthreads();
  if (threadIdx.x == 0) counts[e] = base;
}

// Fused masked-FFN. BT=128 tokens/block, 8 waves, f-chunks of 256, K-panels of 32.
// Swapped operands: A=weights (rows f / d), B=x / h (cols = token).
// Race-free 2-slot pipeline: barrier -> stage(next, other slot) -> vmcnt -> barrier -> compute.
__launch_bounds__(512, 2)
__global__ void moe_ffn(const u16* __restrict__ xbf, const u16* __restrict__ W1p,
                        const float* __restrict__ b1f, const u16* __restrict__ W2p,
                        const float* __restrict__ b2f,
                        const int* __restrict__ idx, const int* __restrict__ counts,
                        float* __restrict__ out) {
  // ---- expert-per-XCD mapping: NE == NXCD == 8 ----
  int e = blockIdx.x & 7;          // XCD x serves expert x (weights fit its 4MB L2)
  int r0 = (blockIdx.x >> 3) << 7; // slot * BT
  if (r0 >= counts[e]) return;
  int rem = counts[e] - r0; if (rem > BT) rem = BT;

  __shared__ __align__(16) u16 arena[2 * 16384];  // 64 KB: weight K-panel slots
  __shared__ __align__(16) u16 xp[2 * 4096];      // 16 KB: x K-panel slots
  __shared__ __align__(16) u16 hs[BT * 256];      // 64 KB: h^T chunk [t][f]
  __shared__ __align__(16) float b1s[NF];
  __shared__ __align__(16) float b2s[ND];
  __shared__ int ids_s[BT];

  int tid = threadIdx.x, lane = tid & 63, w = tid >> 6;
  int wt = w & 1, wfd = w >> 1;   // t-split 2, f/d-split 4
  int l15 = lane & 15, l4 = lane >> 4;

  if (tid < BT) ids_s[tid] = idx[(size_t)e * NT + r0 + ((tid < rem) ? tid : 0)];
  __syncthreads();

  // x stage source (per-lane): wave w stages rows w*16..w*16+15 of the x panel
  const char* xbyte = (const char*)xbf;
  int xrow = w * 16 + (lane >> 2);
  size_t xsrc = (size_t)ids_s[xrow] * (ND * 2) +
                (((lane & 3) * 16) ^ (((xrow >> 1) & 3) << 4));

  // ds-read offsets (byte, slot-relative)
  int aoff1[4], boffx[4], aoff2[8], tbase[4], tswz[4];
  #pragma unroll
  for (int i = 0; i < 4; i++) {
    int rf = wfd * 64 + i * 16 + l15;
    aoff1[i] = rf * 64 + ((l4 * 16) ^ (((rf >> 1) & 3) << 4));
    int t = wt * 64 + i * 16 + l15;
    boffx[i] = t * 64 + ((l4 * 16) ^ (((t >> 1) & 3) << 4));
    tbase[i] = t * 512; tswz[i] = (t & 7) << 4;
  }
  #pragma unroll
  for (int i = 0; i < 8; i++) {
    int rd = wfd * 128 + i * 16 + l15;
    aoff2[i] = rd * 64 + ((l4 * 16) ^ (((rd >> 1) & 3) << 4));
  }

  const char* w1b = (const char*)W1p + (size_t)e * (8 * 16 * 16384);
  const char* w2b = (const char*)W2p + (size_t)e * (8 * 8 * 32768);
  char* arenaB = (char*)arena;
  char* xpB = (char*)xp;
  char* hsB = (char*)hs;

  auto STAGE1 = [&](int c, int kb, int s) {
    const char* pb = w1b + (((size_t)c * 16 + kb) << 14);
    char* lb = arenaB + s * 32768 + w * 2048;
    gl_lds16(pb + w * 2048 + lane * 16, lb);
    gl_lds16(pb + w * 2048 + 1024 + lane * 16, lb + 1024);
    gl_lds16(xbyte + xsrc + kb * 64, xpB + s * 8192 + w * 1024);
  };
  auto STAGE2 = [&](int c, int kb, int s) {
    const char* pb = w2b + (((size_t)c * 8 + kb) << 15);
    char* lb = arenaB + s * 32768 + w * 4096;
    #pragma unroll
    for (int j = 0; j < 4; j++)
      gl_lds16(pb + w * 4096 + j * 1024 + lane * 16, lb + j * 1024);
  };

  // prologue: biases + first GEMM1 panel
  gl_lds16((const char*)(b1f + (size_t)e * NF) + w * 1024, (char*)b1s + w * 1024);
  if (w < 2) gl_lds16((const char*)(b2f + (size_t)e * ND) + w * 1024, (char*)b2s + w * 1024);
  STAGE1(0, 0, 0);

  f32x4 yacc[8][4];
  #pragma unroll
  for (int i = 0; i < 8; i++)
    #pragma unroll
    for (int t = 0; t < 4; t++) yacc[i][t] = (f32x4)(0.0f);

  for (int c = 0; c < 8; ++c) {
    // ---- GEMM1: h^T[256 f x 128 t] = W1-chunk^T x x^T, K=512 over 16 panels ----
    f32x4 acc1[4][4];
    #pragma unroll
    for (int i = 0; i < 4; i++)
      #pragma unroll
      for (int t = 0; t < 4; t++) acc1[i][t] = (f32x4)(0.0f);

    for (int kb = 0; kb < 16; ++kb) {
      int s = kb & 1;
      __builtin_amdgcn_s_barrier();   // all waves done READING slot s^1 (kb-1 compute)
      if (kb < 15) { STAGE1(c, kb + 1, s ^ 1); WAITV(3); }
      else         { STAGE2(c, 0, 0);          WAITV(4); }
      __builtin_amdgcn_s_barrier();   // all waves' portions of slot s landed
      const char* lb = arenaB + s * 32768;
      const char* lx = xpB + s * 8192;
      bf16x8 a[4], b[4];
      #pragma unroll
      for (int i = 0; i < 4; i++) a[i] = *(const bf16x8*)(lb + aoff1[i]);
      #pragma unroll
      for (int t = 0; t < 4; t++) b[t] = *(const bf16x8*)(lx + boffx[t]);
      #pragma unroll
      for (int i = 0; i < 4; i++)
        #pragma unroll
        for (int t = 0; t < 4; t++)
          acc1[i][t] = __builtin_amdgcn_mfma_f32_16x16x32_bf16(a[i], b[t], acc1[i][t], 0, 0, 0);
    }

    // ---- GELU + b1 -> hs[t][f] (packed 4 x u16 = one b64 per fragment) ----
    #pragma unroll
    for (int i = 0; i < 4; i++) {
      int fb = wfd * 64 + i * 16 + l4 * 4;
      f32x4 bv = *(const f32x4*)(b1s + c * 256 + fb);
      #pragma unroll
      for (int t = 0; t < 4; t++) {
        union { u16 s[4]; u64 ll; } pk;
        #pragma unroll
        for (int j = 0; j < 4; j++)
          pk.s[j] = f2bf(gelu_fast(acc1[i][t][j] + bv[j]));
        *(u64*)(hsB + tbase[t] + ((fb * 2) ^ tswz[t])) = pk.ll;
      }
    }
    asm volatile("s_waitcnt lgkmcnt(0)" ::: "memory");
    __builtin_amdgcn_s_barrier();

    // ---- GEMM2: y^T[512 d x 128 t] += W2-chunk^T x h, K=256 over 8 panels ----
    for (int kb = 0; kb < 8; ++kb) {
      int s = kb & 1;
      __builtin_amdgcn_s_barrier();   // slot s^1 readers done
      if (kb < 7)      { STAGE2(c, kb + 1, s ^ 1); WAITV(4); }
      else if (c < 7)  { STAGE1(c + 1, 0, 0);      WAITV(3); }
      else             { WAITV(0); }
      __builtin_amdgcn_s_barrier();   // slot s landed
      const char* lb = arenaB + s * 32768;
      bf16x8 a[8], b[4];
      #pragma unroll
      for (int i = 0; i < 8; i++) a[i] = *(const bf16x8*)(lb + aoff2[i]);
      #pragma unroll
      for (int t = 0; t < 4; t++)
        b[t] = *(const bf16x8*)(hsB + tbase[t] + ((kb * 64 + l4 * 16) ^ tswz[t]));
      #pragma unroll
      for (int i = 0; i < 8; i++)
        #pragma unroll
        for (int t = 0; t < 4; t++)
          yacc[i][t] = __builtin_amdgcn_mfma_f32_16x16x32_bf16(a[i], b[t], yacc[i][t], 0, 0, 0);
    }
  }

  // ---- epilogue: per-token contiguous float4 stores (+b2), guard t < rem ----
  #pragma unroll
  for (int i = 0; i < 8; i++) {
    int db = wfd * 128 + i * 16 + l4 * 4;
    f32x4 b2v = *(const f32x4*)(b2s + db);
    #pragma unroll
    for (int t = 0; t < 4; t++) {
      int tt = wt * 64 + t * 16 + l15;
      if (tt < rem) {
        int tok = ids_s[tt];
        f32x4 v;
        #pragma unroll
        for (int j = 0; j < 4; j++) v[j] = yacc[i][t][j] + b2v[j];
        *(f32x4*)(out + ((size_t)e * NT + tok) * ND + db) = v;
      }
    }
  }
}

extern "C" void kernel_launch(void* const* d_in, const int* in_sizes, int n_in,
                              void* d_out, int out_size, void* d_ws, size_t ws_size,
                              hipStream_t stream) {
  const float* x  = (const float*)d_in[0];
  const float* W1 = (const float*)d_in[1];
  const float* b1 = (const float*)d_in[2];
  const float* W2 = (const float*)d_in[3];
  const float* b2 = (const float*)d_in[4];
  const int* mask = (const int*)d_in[5];

  char* ws = (char*)d_ws;
  int* counts = (int*)ws;                                   // 1 KiB region
  int* idx    = (int*)(ws + 1024);                          // 512 KiB
  u16* W1p    = (u16*)(ws + 1024 + (size_t)NE * NT * 4);    // 16 MiB
  u16* W2p    = W1p + (size_t)NE * NF * ND;                 // 16 MiB
  u16* xbf    = W2p + (size_t)NE * ND * NF;                 // 16 MiB

  zero_unmasked<<<dim3(NE * NT / 2), dim3(256), 0, stream>>>(mask, (float4*)d_out);
  pack_w<0><<<dim3(16, 64, NE), dim3(256), 0, stream>>>(W1, W1p);
  pack_w<1><<<dim3(64, 16, NE), dim3(256), 0, stream>>>(W2, W2p);
  x_to_bf16<<<dim3(NT * ND / 4 / 256), dim3(256), 0, stream>>>(x, xbf);
  compact_mask<<<dim3(NE), dim3(256), 0, stream>>>(mask, idx, counts);
  moe_ffn<<<dim3(2048), dim3(512), 0, stream>>>(xbf, W1p, b1, W2p, b2, idx, counts,
                                                (float*)d_out);
}

// Round 6
// 646.033 us; speedup vs baseline: 1.0293x; 1.0293x over previous
//
#include <hip/hip_runtime.h>
#include <hip/hip_bf16.h>

#define NE 8
#define NT 16384
#define ND 512
#define NF 2048
#define BT 128

typedef __attribute__((ext_vector_type(8))) short bf16x8;
typedef __attribute__((ext_vector_type(4))) float f32x4;
typedef unsigned short u16;
typedef unsigned long long u64;

#define WAITV(n) asm volatile("s_waitcnt vmcnt(" #n ")" ::: "memory")
#define WAITL()  asm volatile("s_waitcnt lgkmcnt(0)" ::: "memory")

__device__ __forceinline__ u16 f2bf(float f) {
  union { float f; unsigned u; } c; c.f = f;
  unsigned u = c.u;
  return (u16)((u + 0x7FFFu + ((u >> 16) & 1u)) >> 16);
}

// gelu(x) = x * (1 - 1/(exp2(K1*x + K2*x^3) + 1)),  K1 = sqrt(2/pi)*2*log2e
__device__ __forceinline__ float gelu_fast(float x) {
  float x2 = x * x;
  float zp = x * __builtin_fmaf(0.10294325f, x2, 2.3022084f);
  float u = __builtin_amdgcn_exp2f(zp);
  float r = __builtin_amdgcn_rcpf(u + 1.0f);   // u=inf -> r=0 -> y=x
  return x * (1.0f - r);
}

__device__ __forceinline__ void gl_lds16(const void* g, void* l) {
  __builtin_amdgcn_global_load_lds(
      (const __attribute__((address_space(1))) unsigned int*)g,
      (__attribute__((address_space(3))) unsigned int*)l, 16, 0, 0);
}

// Pack weights into staged-panel images (swizzle pre-applied, byte-exact LDS image).
// MODE 0: W1 [E][512 d][2048 f] -> panels (e, c=f/256, kb=d/32): [256 f][32 d] bf16, 16 KB.
// MODE 1: W2 [E][2048 f][512 d] -> panels (e, c=f/256, kb=(f%256)/32): [512 d][32 f] bf16, 32 KB.
template<int MODE>
__global__ void pack_w(const float* __restrict__ in, u16* __restrict__ outp) {
  constexpr int K = MODE ? 2048 : 512;
  constexpr int R = MODE ? 512 : 2048;
  __shared__ float tile[32][33];
  int e = blockIdx.z, bx = blockIdx.x, by = blockIdx.y;
  int k0 = bx * 32, r0 = by * 32;
  int tx = threadIdx.x & 31, ty = threadIdx.x >> 5;
  const float* ip = in + ((size_t)e * K + k0) * R + r0;
  #pragma unroll
  for (int i = 0; i < 4; i++)
    tile[ty + i * 8][tx] = ip[(size_t)(ty + i * 8) * R + tx];
  __syncthreads();
  size_t base; int rowb;
  if (MODE == 0) { base = (((size_t)e * 8 + (by >> 3)) * 16 + bx) * 8192; rowb = (by & 7) * 32; }
  else           { base = (((size_t)e * 8 + (bx >> 3)) * 8 + (bx & 7)) * 16384; rowb = by * 32; }
  int row = rowb + tx;
  int byo = row * 64 + ((ty * 8) ^ (((row >> 1) & 3) << 4));
  union { u16 s[4]; ushort4 v; } o;
  #pragma unroll
  for (int j = 0; j < 4; j++) o.s[j] = f2bf(tile[ty * 4 + j][tx]);
  *(ushort4*)((char*)outp + base * 2 + byo) = o.v;
}

__global__ void x_to_bf16(const float* __restrict__ x, u16* __restrict__ xbf) {
  int i = blockIdx.x * 256 + threadIdx.x;
  float4 v = ((const float4*)x)[i];
  union { u16 s[4]; u64 ll; } o;
  o.s[0] = f2bf(v.x); o.s[1] = f2bf(v.y); o.s[2] = f2bf(v.z); o.s[3] = f2bf(v.w);
  ((u64*)xbf)[i] = o.ll;
}

__global__ void zero_unmasked(const int* __restrict__ mask, float4* __restrict__ out4) {
  int row = blockIdx.x * 2 + (threadIdx.x >> 7);
  if (mask[row]) return;  // masked rows fully written by moe_ffn
  out4[(size_t)row * 128 + (threadIdx.x & 127)] = float4{0.f, 0.f, 0.f, 0.f};
}

__global__ void compact_mask(const int* __restrict__ mask, int* __restrict__ idx,
                             int* __restrict__ counts) {
  int e = blockIdx.x;
  __shared__ int wsum[4];
  __shared__ int base;
  if (threadIdx.x == 0) base = 0;
  const int* m = mask + (size_t)e * NT;
  int lane = threadIdx.x & 63, w = threadIdx.x >> 6;
  for (int c0 = 0; c0 < NT; c0 += 256) {
    __syncthreads();
    int i = c0 + threadIdx.x;
    int mi = (m[i] != 0);
    unsigned long long b = __ballot(mi);
    if (lane == 0) wsum[w] = __popcll(b);
    __syncthreads();
    int off = base;
    for (int ww = 0; ww < w; ww++) off += wsum[ww];
    off += __popcll(b & ((1ull << lane) - 1ull));
    if (mi) idx[(size_t)e * NT + off] = i;
    __syncthreads();
    if (threadIdx.x == 0) base += wsum[0] + wsum[1] + wsum[2] + wsum[3];
  }
  __syncthreads();
  if (threadIdx.x == 0) counts[e] = base;
}

// Fused masked-FFN. BT=128 tokens/block, 8 waves, f-chunks of 256, K-panels of 32.
// Swapped operands: A=weights (rows f / d), B=x / h (cols = token).
// Single-barrier 2-slot pipeline (T3 2-phase recipe):
//   STAGE(next -> s^1); ds_read+MFMA(slot s); lgkmcnt(0); vmcnt(0); barrier.
__launch_bounds__(512, 2)
__global__ void moe_ffn(const u16* __restrict__ xbf, const u16* __restrict__ W1p,
                        const float* __restrict__ b1f, const u16* __restrict__ W2p,
                        const float* __restrict__ b2f,
                        const int* __restrict__ idx, const int* __restrict__ counts,
                        float* __restrict__ out) {
  // ---- identity prefix mapping: active work = contiguous low block IDs ----
  int b = blockIdx.x;
  int e = 0, r0 = 0, start = 0; bool act = false;
  #pragma unroll
  for (int ee = 0; ee < 8; ee++) {
    int nb = (counts[ee] + (BT - 1)) >> 7;
    if (!act && b < start + nb) { e = ee; r0 = (b - start) << 7; act = true; }
    start += nb;
  }
  if (!act) return;
  int rem = counts[e] - r0; if (rem > BT) rem = BT;

  // LDS: arena 64KB (G1: 2x16KB slots at 0,16K; G2: 2x32KB slots at 0,32K)
  __shared__ __align__(16) u16 arena[32768];      // 64 KB
  __shared__ __align__(16) u16 xp[2 * 4096];      // 16 KB: x K-panel slots
  __shared__ __align__(16) u16 hs[BT * 256];      // 64 KB: h^T chunk [t][f]
  __shared__ __align__(16) float b1s[NF];         // 8 KB
  __shared__ __align__(16) float b2s[ND];         // 2 KB
  __shared__ int ids_s[BT];

  int tid = threadIdx.x, lane = tid & 63, w = tid >> 6;
  int wt = w & 1, wfd = w >> 1;   // t-split 2, f/d-split 4
  int l15 = lane & 15, l4 = lane >> 4;

  if (tid < BT) ids_s[tid] = idx[(size_t)e * NT + r0 + ((tid < rem) ? tid : 0)];
  __syncthreads();

  // x stage source (per-lane): wave w stages rows w*16..w*16+15 of the x panel
  const char* xbyte = (const char*)xbf;
  int xrow = w * 16 + (lane >> 2);
  size_t xsrc = (size_t)ids_s[xrow] * (ND * 2) +
                (((lane & 3) * 16) ^ (((xrow >> 1) & 3) << 4));

  // ds-read offsets (byte, slot-relative)
  int aoff1[4], boffx[4], aoff2[8], tbase[4], tswz[4];
  #pragma unroll
  for (int i = 0; i < 4; i++) {
    int rf = wfd * 64 + i * 16 + l15;
    aoff1[i] = rf * 64 + ((l4 * 16) ^ (((rf >> 1) & 3) << 4));
    int t = wt * 64 + i * 16 + l15;
    boffx[i] = t * 64 + ((l4 * 16) ^ (((t >> 1) & 3) << 4));
    tbase[i] = t * 512; tswz[i] = (t & 7) << 4;
  }
  #pragma unroll
  for (int i = 0; i < 8; i++) {
    int rd = wfd * 128 + i * 16 + l15;
    aoff2[i] = rd * 64 + ((l4 * 16) ^ (((rd >> 1) & 3) << 4));
  }

  const char* w1b = (const char*)W1p + (size_t)e * (8 * 16 * 16384);
  const char* w2b = (const char*)W2p + (size_t)e * (8 * 8 * 32768);
  char* arenaB = (char*)arena;
  char* xpB = (char*)xp;
  char* hsB = (char*)hs;

  auto STAGE1 = [&](int c, int kb, int s) {   // W1 16KB panel -> [s*16K, +16K) + x 8KB
    const char* pb = w1b + (((size_t)c * 16 + kb) << 14);
    char* lb = arenaB + s * 16384 + w * 2048;
    gl_lds16(pb + w * 2048 + lane * 16, lb);
    gl_lds16(pb + w * 2048 + 1024 + lane * 16, lb + 1024);
    gl_lds16(xbyte + xsrc + kb * 64, xpB + s * 8192 + w * 1024);
  };
  auto STAGE2 = [&](int c, int kb, int s) {   // W2 32KB panel -> [s*32K, +32K)
    const char* pb = w2b + (((size_t)c * 8 + kb) << 15);
    char* lb = arenaB + s * 32768 + w * 4096;
    #pragma unroll
    for (int j = 0; j < 4; j++)
      gl_lds16(pb + w * 4096 + j * 1024 + lane * 16, lb + j * 1024);
  };

  // prologue: biases + G1 panel 0
  gl_lds16((const char*)(b1f + (size_t)e * NF) + w * 1024, (char*)b1s + w * 1024);
  if (w < 2) gl_lds16((const char*)(b2f + (size_t)e * ND) + w * 1024, (char*)b2s + w * 1024);
  STAGE1(0, 0, 0);
  WAITV(0);
  __builtin_amdgcn_s_barrier();

  f32x4 yacc[8][4];
  #pragma unroll
  for (int i = 0; i < 8; i++)
    #pragma unroll
    for (int t = 0; t < 4; t++) yacc[i][t] = (f32x4)(0.0f);

  for (int c = 0; c < 8; ++c) {
    // ---- GEMM1: h^T[256 f x 128 t] = W1-chunk^T x x^T, K=512 over 16 panels ----
    f32x4 acc1[4][4];
    #pragma unroll
    for (int i = 0; i < 4; i++)
      #pragma unroll
      for (int t = 0; t < 4; t++) acc1[i][t] = (f32x4)(0.0f);

    for (int kb = 0; kb < 16; ++kb) {
      int s = kb & 1;
      if (kb < 15) STAGE1(c, kb + 1, s ^ 1);   // writes slot s^1: readers done at kb-1
      const char* lb = arenaB + s * 16384;
      const char* lx = xpB + s * 8192;
      bf16x8 a[4], bb[4];
      #pragma unroll
      for (int i = 0; i < 4; i++) a[i] = *(const bf16x8*)(lb + aoff1[i]);
      #pragma unroll
      for (int t = 0; t < 4; t++) bb[t] = *(const bf16x8*)(lx + boffx[t]);
      #pragma unroll
      for (int i = 0; i < 4; i++)
        #pragma unroll
        for (int t = 0; t < 4; t++)
          acc1[i][t] = __builtin_amdgcn_mfma_f32_16x16x32_bf16(a[i], bb[t], acc1[i][t], 0, 0, 0);
      WAITL(); WAITV(0);
      __builtin_amdgcn_s_barrier();
    }

    // ---- GELU phase: prestage G2 panel0 into [0,32K) (G1 slots: readers done) ----
    STAGE2(c, 0, 0);
    #pragma unroll
    for (int i = 0; i < 4; i++) {
      int fb = wfd * 64 + i * 16 + l4 * 4;
      f32x4 bv = *(const f32x4*)(b1s + c * 256 + fb);
      #pragma unroll
      for (int t = 0; t < 4; t++) {
        union { u16 s[4]; u64 ll; } pk;
        #pragma unroll
        for (int j = 0; j < 4; j++)
          pk.s[j] = f2bf(gelu_fast(acc1[i][t][j] + bv[j]));
        *(u64*)(hsB + tbase[t] + ((fb * 2) ^ tswz[t])) = pk.ll;
      }
    }
    WAITL(); WAITV(0);
    __builtin_amdgcn_s_barrier();

    // ---- GEMM2: y^T[512 d x 128 t] += W2-chunk^T x h, K=256 over 8 panels ----
    for (int kb = 0; kb < 8; ++kb) {
      int s = kb & 1;
      if (kb < 7)     STAGE2(c, kb + 1, s ^ 1);  // slot s^1: readers done at kb-1
      else if (c < 7) STAGE1(c + 1, 0, 0);       // [0,16K)+xp0: readers done (kb=6 / G1 kb=14)
      const char* lb = arenaB + s * 32768;
      bf16x8 a[8], bb[4];
      #pragma unroll
      for (int i = 0; i < 8; i++) a[i] = *(const bf16x8*)(lb + aoff2[i]);
      #pragma unroll
      for (int t = 0; t < 4; t++)
        bb[t] = *(const bf16x8*)(hsB + tbase[t] + ((kb * 64 + l4 * 16) ^ tswz[t]));
      #pragma unroll
      for (int i = 0; i < 8; i++)
        #pragma unroll
        for (int t = 0; t < 4; t++)
          yacc[i][t] = __builtin_amdgcn_mfma_f32_16x16x32_bf16(a[i], bb[t], yacc[i][t], 0, 0, 0);
      WAITL(); WAITV(0);
      __builtin_amdgcn_s_barrier();
    }
  }

  // ---- epilogue: per-token contiguous float4 stores (+b2), guard t < rem ----
  #pragma unroll
  for (int i = 0; i < 8; i++) {
    int db = wfd * 128 + i * 16 + l4 * 4;
    f32x4 b2v = *(const f32x4*)(b2s + db);
    #pragma unroll
    for (int t = 0; t < 4; t++) {
      int tt = wt * 64 + t * 16 + l15;
      if (tt < rem) {
        int tok = ids_s[tt];
        f32x4 v;
        #pragma unroll
        for (int j = 0; j < 4; j++) v[j] = yacc[i][t][j] + b2v[j];
        *(f32x4*)(out + ((size_t)e * NT + tok) * ND + db) = v;
      }
    }
  }
}

extern "C" void kernel_launch(void* const* d_in, const int* in_sizes, int n_in,
                              void* d_out, int out_size, void* d_ws, size_t ws_size,
                              hipStream_t stream) {
  const float* x  = (const float*)d_in[0];
  const float* W1 = (const float*)d_in[1];
  const float* b1 = (const float*)d_in[2];
  const float* W2 = (const float*)d_in[3];
  const float* b2 = (const float*)d_in[4];
  const int* mask = (const int*)d_in[5];

  char* ws = (char*)d_ws;
  int* counts = (int*)ws;                                   // 1 KiB region
  int* idx    = (int*)(ws + 1024);                          // 512 KiB
  u16* W1p    = (u16*)(ws + 1024 + (size_t)NE * NT * 4);    // 16 MiB
  u16* W2p    = W1p + (size_t)NE * NF * ND;                 // 16 MiB
  u16* xbf    = W2p + (size_t)NE * ND * NF;                 // 16 MiB

  zero_unmasked<<<dim3(NE * NT / 2), dim3(256), 0, stream>>>(mask, (float4*)d_out);
  pack_w<0><<<dim3(16, 64, NE), dim3(256), 0, stream>>>(W1, W1p);
  pack_w<1><<<dim3(64, 16, NE), dim3(256), 0, stream>>>(W2, W2p);
  x_to_bf16<<<dim3(NT * ND / 4 / 256), dim3(256), 0, stream>>>(x, xbf);
  compact_mask<<<dim3(NE), dim3(256), 0, stream>>>(mask, idx, counts);
  moe_ffn<<<dim3(1024), dim3(512), 0, stream>>>(xbf, W1p, b1, W2p, b2, idx, counts,
                                                (float*)d_out);
}